// Round 7
// baseline (468.487 us; speedup 1.0000x reference)
//
#include <hip/hip_runtime.h>
#include <math.h>

constexpr int NN = 20000;   // nodes
constexpr int NE = 320000;  // edges
constexpr int MPAD = 20096; // row padding for A-type buffers (>= 313*64+63)

typedef __bf16 bf16x8 __attribute__((ext_vector_type(8)));
typedef float f32x4 __attribute__((ext_vector_type(4)));

__device__ __forceinline__ unsigned short f2bf(float f) {
  unsigned int u = __float_as_uint(f);
  unsigned int r = (u + 0x7FFFu + ((u >> 16) & 1u)) >> 16;
  return (unsigned short)r;
}
__device__ __forceinline__ float bf2f(unsigned short s) {
  return __uint_as_float(((unsigned int)s) << 16);
}

// ---------------- degree count ----------------
__global__ void deg_count_kernel(const int* __restrict__ src, const int* __restrict__ dst,
                                 int* __restrict__ degs, int* __restrict__ degd, int nE) {
  int e = blockIdx.x * blockDim.x + threadIdx.x;
  if (e < nE) {
    atomicAdd(degs + src[e], 1);
    atomicAdd(degd + dst[e], 1);
  }
}

__global__ void norm_kernel(const int* __restrict__ degs, const int* __restrict__ degd,
                            float* __restrict__ ns, float* __restrict__ nd, int n) {
  int i = blockIdx.x * blockDim.x + threadIdx.x;
  if (i < n) {
    ns[i] = rsqrtf(fmaxf((float)degs[i], 1.0f));
    nd[i] = rsqrtf(fmaxf((float)degd[i], 1.0f));
  }
}

// ---------------- single-block exclusive scan -> rowptr ----------------
__global__ __launch_bounds__(1024) void scan_kernel(const int* __restrict__ deg,
                                                    int* __restrict__ rowptr, int n) {
  constexpr int T = 1024;
  const int ITEMS = (n + T - 1) / T;
  __shared__ int sums[T];
  int t = threadIdx.x;
  int base = t * ITEMS;
  int s = 0;
  for (int i = 0; i < ITEMS; ++i) {
    int idx = base + i;
    if (idx < n) s += deg[idx];
  }
  sums[t] = s;
  __syncthreads();
  for (int off = 1; off < T; off <<= 1) {
    int v = (t >= off) ? sums[t - off] : 0;
    __syncthreads();
    sums[t] += v;
    __syncthreads();
  }
  int ex = (t == 0) ? 0 : sums[t - 1];
  for (int i = 0; i < ITEMS; ++i) {
    int idx = base + i;
    if (idx < n) {
      rowptr[idx] = ex;
      ex += deg[idx];
    }
  }
  if (t == 0) rowptr[n] = sums[T - 1];
}

// ---------------- CSR fill ----------------
__global__ void csr_fill_kernel(const int* __restrict__ src, const int* __restrict__ dst,
                                const int* __restrict__ rowptr, int* __restrict__ cursor,
                                int* __restrict__ col, int nE) {
  int e = blockIdx.x * blockDim.x + threadIdx.x;
  if (e < nE) {
    int d = dst[e];
    int p = atomicAdd(cursor + d, 1);
    col[rowptr[d] + p] = src[e];
  }
}

// ---------------- weight convert: W[K][N] f32 -> Wt[Npad][Kpad] bf16 (zero pad) -------
__global__ void wt_convert_kernel(const float* __restrict__ W, unsigned short* __restrict__ Wt,
                                  int K, int N, int Kpad) {
  int k = blockIdx.x * 256 + threadIdx.x;
  int n = blockIdx.y;
  if (k >= Kpad) return;
  float v = (n < N && k < K) ? W[(size_t)k * N + n] : 0.f;
  Wt[(size_t)n * Kpad + k] = f2bf(v);
}

// ---------------- CSR gather aggregation ----------------
// EPI==0: write raw sum (f32 or bf16 per OUT_BF).
// EPI==1: v=sum*sDst+b -> out (f32 or bf16 per OUT_BF) AND sigmoid(v)->out2 (f32).
// EPI==2: v=sum*sDst+b -> sigmoid(v)->out2 only.
template <int F, int SCALE_SRC, int EPI, int OUT_BF, int IN_BF>
__global__ __launch_bounds__(256) void gather_kernel(
    const void* __restrict__ in, const float* __restrict__ sSrc,
    const int* __restrict__ rowptr, const int* __restrict__ col,
    const float* __restrict__ sDst, const float* __restrict__ bias,
    void* __restrict__ out, float* __restrict__ out2, int n) {
  constexpr int F4 = F / 4;
  constexpr int NPB = 256 / F4;
  int tid = threadIdx.x;
  int node = blockIdx.x * NPB + tid / F4;
  int j = tid % F4;
  if (node >= n) return;
  int e0 = rowptr[node], e1 = rowptr[node + 1];
  float4 acc = make_float4(0.f, 0.f, 0.f, 0.f);
  for (int e = e0; e < e1; ++e) {
    int c = col[e];
    float4 v;
    if (IN_BF) {
      ushort4 u = reinterpret_cast<const ushort4*>(in)[(size_t)c * F4 + j];
      v = make_float4(bf2f(u.x), bf2f(u.y), bf2f(u.z), bf2f(u.w));
    } else {
      v = reinterpret_cast<const float4*>(in)[(size_t)c * F4 + j];
    }
    if (SCALE_SRC) {
      float sc = sSrc[c];
      v.x *= sc; v.y *= sc; v.z *= sc; v.w *= sc;
    }
    acc.x += v.x; acc.y += v.y; acc.z += v.z; acc.w += v.w;
  }
  if (EPI == 0) {
    if (OUT_BF) {
      ushort4 p;
      p.x = f2bf(acc.x); p.y = f2bf(acc.y); p.z = f2bf(acc.z); p.w = f2bf(acc.w);
      reinterpret_cast<ushort4*>(out)[(size_t)node * F4 + j] = p;
    } else {
      reinterpret_cast<float4*>(out)[(size_t)node * F4 + j] = acc;
    }
    return;
  }
  float sd = sDst[node];
  float4 bb = reinterpret_cast<const float4*>(bias)[j];
  acc.x = acc.x * sd + bb.x;
  acc.y = acc.y * sd + bb.y;
  acc.z = acc.z * sd + bb.z;
  acc.w = acc.w * sd + bb.w;
  if (EPI == 1) {
    if (OUT_BF) {
      ushort4 p;
      p.x = f2bf(acc.x); p.y = f2bf(acc.y); p.z = f2bf(acc.z); p.w = f2bf(acc.w);
      reinterpret_cast<ushort4*>(out)[(size_t)node * F4 + j] = p;
    } else {
      reinterpret_cast<float4*>(out)[(size_t)node * F4 + j] = acc;
    }
  }
  float4 o;
  o.x = 1.0f / (1.0f + expf(-acc.x));
  o.y = 1.0f / (1.0f + expf(-acc.y));
  o.z = 1.0f / (1.0f + expf(-acc.z));
  o.w = 1.0f / (1.0f + expf(-acc.w));
  reinterpret_cast<float4*>(out2)[(size_t)node * F4 + j] = o;
}

// ---------------- bf16 MFMA GEMM, max-TLP: 16x64 per wave, LDS-free ----------------
// C[M,N] = epi(A[M,K] @ Bt[>=gridX*64, K]^T), K = NT_*32.
// Block = 256 thr = 4 waves stacked in M (block tile 64 x 64). Grid (ceil(N.../64), ceil(M/64)).
// Per wave: 1x4 16x16 frags -> acc = 16 AGPR, ~50 VGPR -> high occupancy; latency
// hidden by wave count (TLP), not intra-wave pipelining. No LDS, no barriers.
// Frags loaded directly global->VGPR (16 B/lane, contiguous along K for A and Bt).
// epi: v = acc*rowscale[r] + bias[c]; RELU; stores guarded r<M, c<N.
template <int NT_, int OUT_BF, int RELU>
__global__ __launch_bounds__(256) void gemm5_kernel(
    const unsigned short* __restrict__ A, const unsigned short* __restrict__ Bt,
    void* __restrict__ C, int M, int N,
    const float* __restrict__ rowscale, const float* __restrict__ bias) {
  constexpr int K = NT_ * 32;
  const int l = threadIdx.x & 63, w = threadIdx.x >> 6;
  const int lrow = l & 15, k16 = l >> 4;
  const int bm = blockIdx.y * 64, bn = blockIdx.x * 64;
  const unsigned short* ap = A + (size_t)(bm + w * 16 + lrow) * K + k16 * 8;
  const unsigned short* bp = Bt + (size_t)(bn + lrow) * K + k16 * 8;

  f32x4 acc[4] = {};
#pragma unroll
  for (int t = 0; t < NT_; ++t) {
    bf16x8 a  = *reinterpret_cast<const bf16x8*>(ap + t * 32);
    bf16x8 b0 = *reinterpret_cast<const bf16x8*>(bp + t * 32);
    bf16x8 b1 = *reinterpret_cast<const bf16x8*>(bp + (size_t)16 * K + t * 32);
    bf16x8 b2 = *reinterpret_cast<const bf16x8*>(bp + (size_t)32 * K + t * 32);
    bf16x8 b3 = *reinterpret_cast<const bf16x8*>(bp + (size_t)48 * K + t * 32);
    acc[0] = __builtin_amdgcn_mfma_f32_16x16x32_bf16(a, b0, acc[0], 0, 0, 0);
    acc[1] = __builtin_amdgcn_mfma_f32_16x16x32_bf16(a, b1, acc[1], 0, 0, 0);
    acc[2] = __builtin_amdgcn_mfma_f32_16x16x32_bf16(a, b2, acc[2], 0, 0, 0);
    acc[3] = __builtin_amdgcn_mfma_f32_16x16x32_bf16(a, b3, acc[3], 0, 0, 0);
  }

  // C/D layout (verified r3-r6): row_in_frag = k16*4 + q, col_in_frag = lrow.
#pragma unroll
  for (int q = 0; q < 4; ++q) {
    int r = bm + w * 16 + k16 * 4 + q;
    if (r >= M) continue;
    float rs = rowscale[r];
#pragma unroll
    for (int ni = 0; ni < 4; ++ni) {
      int c = bn + ni * 16 + lrow;
      if (c >= N) continue;
      float v = acc[ni][q] * rs;
      if (bias) v += bias[c];
      if (RELU) v = fmaxf(v, 0.f);
      if (OUT_BF) ((unsigned short*)C)[(size_t)r * N + c] = f2bf(v);
      else ((float*)C)[(size_t)r * N + c] = v;
    }
  }
}

extern "C" void kernel_launch(void* const* d_in, const int* in_sizes, int n_in,
                              void* d_out, int out_size, void* d_ws, size_t ws_size,
                              hipStream_t stream) {
  const float* x  = (const float*)d_in[0];
  const int* src  = (const int*)d_in[1];
  const int* dst  = (const int*)d_in[2];
  const float* W1 = (const float*)d_in[3];
  const float* b1 = (const float*)d_in[4];
  const float* W2 = (const float*)d_in[5];
  const float* b2 = (const float*)d_in[6];
  const float* W3 = (const float*)d_in[7];
  const float* b3 = (const float*)d_in[8];
  const float* W4 = (const float*)d_in[9];
  const float* b4 = (const float*)d_in[10];

  float* out_enc = (float*)d_out;                  // [NN,128]
  float* out_dec = out_enc + (size_t)NN * 128;     // [NN,256]

  // ---- workspace layout (~76 MB) ----
  float* ns = (float*)d_ws;                        // [NN]
  float* nd = ns + NN;                             // [NN]
  float* T2 = nd + NN;                             // [NN*128] f32 (GEMM2 out)
  unsigned short* h2  = (unsigned short*)(T2 + (size_t)NN * 128); // [NN*128] bf16 pre-sigmoid
  unsigned short* A1  = h2 + (size_t)NN * 128;     // [MPAD*256] bf16
  unsigned short* A3  = A1 + (size_t)MPAD * 256;   // [MPAD*128] bf16
  unsigned short* G4  = A3 + (size_t)MPAD * 128;   // [NN*256] bf16 (GEMM4 out)
  unsigned short* H1  = G4 + (size_t)NN * 256;     // [MPAD*800] bf16 (GEMM1/3 out)
  unsigned short* W1t = H1 + (size_t)MPAD * 800;   // [896*256]
  unsigned short* W2t = W1t + 896 * 256;           // [128*800]
  unsigned short* W3t = W2t + 128 * 800;           // [896*128]
  unsigned short* W4t = W3t + 896 * 128;           // [256*800]
  int* degs   = (int*)(W4t + 256 * 800);           // [NN]
  int* degd   = degs + NN;                         // [NN]
  int* cursor = degd + NN;                         // [NN]
  int* rowptr = cursor + NN;                       // [NN+1]
  int* col    = rowptr + NN + 1;                   // [NE]

  // ---- CSR build + norms ----
  hipMemsetAsync(degs, 0, 3 * NN * sizeof(int), stream);
  deg_count_kernel<<<(NE + 255) / 256, 256, 0, stream>>>(src, dst, degs, degd, NE);
  norm_kernel<<<(NN + 255) / 256, 256, 0, stream>>>(degs, degd, ns, nd, NN);
  scan_kernel<<<1, 1024, 0, stream>>>(degd, rowptr, NN);
  csr_fill_kernel<<<(NE + 255) / 256, 256, 0, stream>>>(src, dst, rowptr, cursor, col, NE);

  // ---- weight conversion (transpose + pad + bf16) ----
  wt_convert_kernel<<<dim3(1, 896), 256, 0, stream>>>(W1, W1t, 256, 800, 256);
  wt_convert_kernel<<<dim3(4, 128), 256, 0, stream>>>(W2, W2t, 800, 128, 800);
  wt_convert_kernel<<<dim3(1, 896), 256, 0, stream>>>(W3, W3t, 128, 800, 128);
  wt_convert_kernel<<<dim3(4, 256), 256, 0, stream>>>(W4, W4t, 800, 256, 800);

  const int GY = (NN + 63) / 64;  // 313 row-bands of 64 (A-loads stay < MPAD)

  // ---- L1: gather(x*ns) -> bf16 A1; GEMM1 (K=256 -> 800) relu -> H1 ----
  gather_kernel<256, 1, 0, 1, 0><<<(NN + 3) / 4, 256, 0, stream>>>(
      x, ns, rowptr, col, nullptr, nullptr, A1, nullptr, NN);
  gemm5_kernel<8, 1, 1><<<dim3(14, GY), 256, 0, stream>>>(
      A1, W1t, H1, NN, 800, nd, b1);

  // ---- L2: GEMM2 (K=800 -> 128)*ns -> f32 T2; gather -> bf16 h2 + sigmoid(out_enc) ----
  gemm5_kernel<25, 0, 0><<<dim3(2, GY), 256, 0, stream>>>(
      H1, W2t, T2, NN, 128, ns, nullptr);
  gather_kernel<128, 0, 1, 1, 0><<<(NN + 7) / 8, 256, 0, stream>>>(
      T2, nullptr, rowptr, col, nd, b2, h2, out_enc, NN);

  // ---- L3: gather(h2*ns) -> bf16 A3; GEMM3 (K=128 -> 800) relu -> H1 ----
  gather_kernel<128, 1, 0, 1, 1><<<(NN + 7) / 8, 256, 0, stream>>>(
      h2, ns, rowptr, col, nullptr, nullptr, A3, nullptr, NN);
  gemm5_kernel<4, 1, 1><<<dim3(14, GY), 256, 0, stream>>>(
      A3, W3t, H1, NN, 800, nd, b3);

  // ---- L4: GEMM4 (K=800 -> 256)*ns -> bf16 G4; gather -> sigmoid(out_dec) ----
  gemm5_kernel<25, 1, 0><<<dim3(4, GY), 256, 0, stream>>>(
      H1, W4t, G4, NN, 256, ns, nullptr);
  gather_kernel<256, 0, 2, 0, 1><<<(NN + 3) / 4, 256, 0, stream>>>(
      G4, nullptr, rowptr, col, nd, b4, nullptr, out_dec, NN);
}

// Round 9
// 433.909 us; speedup vs baseline: 1.0797x; 1.0797x over previous
//
#include <hip/hip_runtime.h>
#include <math.h>

constexpr int NN = 20000;   // nodes
constexpr int NE = 320000;  // edges
constexpr int MROWS = 20224; // A-buffer rows: 316 bands of 64
constexpr int MH = 20096;   // H1 rows: 628 tiles of 32

typedef __bf16 bf16x8 __attribute__((ext_vector_type(8)));
typedef float f32x4 __attribute__((ext_vector_type(4)));
typedef unsigned short u16x4 __attribute__((ext_vector_type(4)));

__device__ __forceinline__ unsigned short f2bf(float f) {
  unsigned int u = __float_as_uint(f);
  unsigned int r = (u + 0x7FFFu + ((u >> 16) & 1u)) >> 16;
  return (unsigned short)r;
}
__device__ __forceinline__ float bf2f(unsigned short s) {
  return __uint_as_float(((unsigned int)s) << 16);
}

__device__ __forceinline__ void nt_store_f4(float4 v, float* p) {
  f32x4 t; t[0] = v.x; t[1] = v.y; t[2] = v.z; t[3] = v.w;
  __builtin_nontemporal_store(t, (f32x4*)p);
}
__device__ __forceinline__ void nt_store_u4(ushort4 v, unsigned short* p) {
  u16x4 t; t[0] = v.x; t[1] = v.y; t[2] = v.z; t[3] = v.w;
  __builtin_nontemporal_store(t, (u16x4*)p);
}

// bijective XCD chunking (m204): consecutive output indices land on one XCD
__device__ __forceinline__ int xcd_swizzle(int bid, int T) {
  int q = T >> 3, r = T & 7;
  int x = bid & 7, i = bid >> 3;
  return (x < r ? x * (q + 1) : r * (q + 1) + (x - r) * q) + i;
}

// ---------------- degree count ----------------
__global__ void deg_count_kernel(const int* __restrict__ src, const int* __restrict__ dst,
                                 int* __restrict__ degs, int* __restrict__ degd, int nE) {
  int e = blockIdx.x * blockDim.x + threadIdx.x;
  if (e < nE) {
    atomicAdd(degs + src[e], 1);
    atomicAdd(degd + dst[e], 1);
  }
}

__global__ void norm_kernel(const int* __restrict__ degs, const int* __restrict__ degd,
                            float* __restrict__ ns, float* __restrict__ nd, int n) {
  int i = blockIdx.x * blockDim.x + threadIdx.x;
  if (i < n) {
    ns[i] = rsqrtf(fmaxf((float)degs[i], 1.0f));
    nd[i] = rsqrtf(fmaxf((float)degd[i], 1.0f));
  }
}

// ---------------- single-block exclusive scan -> rowptr ----------------
__global__ __launch_bounds__(1024) void scan_kernel(const int* __restrict__ deg,
                                                    int* __restrict__ rowptr, int n) {
  constexpr int T = 1024;
  const int ITEMS = (n + T - 1) / T;
  __shared__ int sums[T];
  int t = threadIdx.x;
  int base = t * ITEMS;
  int s = 0;
  for (int i = 0; i < ITEMS; ++i) {
    int idx = base + i;
    if (idx < n) s += deg[idx];
  }
  sums[t] = s;
  __syncthreads();
  for (int off = 1; off < T; off <<= 1) {
    int v = (t >= off) ? sums[t - off] : 0;
    __syncthreads();
    sums[t] += v;
    __syncthreads();
  }
  int ex = (t == 0) ? 0 : sums[t - 1];
  for (int i = 0; i < ITEMS; ++i) {
    int idx = base + i;
    if (idx < n) {
      rowptr[idx] = ex;
      ex += deg[idx];
    }
  }
  if (t == 0) rowptr[n] = sums[T - 1];
}

// ---------------- CSR fill ----------------
__global__ void csr_fill_kernel(const int* __restrict__ src, const int* __restrict__ dst,
                                const int* __restrict__ rowptr, int* __restrict__ cursor,
                                int* __restrict__ col, int nE) {
  int e = blockIdx.x * blockDim.x + threadIdx.x;
  if (e < nE) {
    int d = dst[e];
    int p = atomicAdd(cursor + d, 1);
    col[rowptr[d] + p] = src[e];
  }
}

// ---------------- weight convert: W[K][N] f32 -> Wt[Npad][Kpad] bf16 (zero pad) -------
__global__ void wt_convert_kernel(const float* __restrict__ W, unsigned short* __restrict__ Wt,
                                  int K, int N, int Kpad) {
  int k = blockIdx.x * 256 + threadIdx.x;
  int n = blockIdx.y;
  if (k >= Kpad) return;
  float v = (n < N && k < K) ? W[(size_t)k * N + n] : 0.f;
  Wt[(size_t)n * Kpad + k] = f2bf(v);
}

// ---------------- CSR gather aggregation (nt-stores on outputs) ----------------
// EPI==0: raw sum -> out. EPI==1: v=sum*sDst+b -> out AND sigmoid(v)->out2.
// EPI==2: v=sum*sDst+b -> sigmoid(v)->out2 only.
template <int F, int SCALE_SRC, int EPI, int OUT_BF, int IN_BF>
__global__ __launch_bounds__(256) void gather_kernel(
    const void* __restrict__ in, const float* __restrict__ sSrc,
    const int* __restrict__ rowptr, const int* __restrict__ col,
    const float* __restrict__ sDst, const float* __restrict__ bias,
    void* __restrict__ out, float* __restrict__ out2, int n) {
  constexpr int F4 = F / 4;
  constexpr int NPB = 256 / F4;
  int tid = threadIdx.x;
  int node = blockIdx.x * NPB + tid / F4;
  int j = tid % F4;
  if (node >= n) return;
  int e0 = rowptr[node], e1 = rowptr[node + 1];
  float4 acc = make_float4(0.f, 0.f, 0.f, 0.f);
  for (int e = e0; e < e1; ++e) {
    int c = col[e];
    float4 v;
    if (IN_BF) {
      ushort4 u = reinterpret_cast<const ushort4*>(in)[(size_t)c * F4 + j];
      v = make_float4(bf2f(u.x), bf2f(u.y), bf2f(u.z), bf2f(u.w));
    } else {
      v = reinterpret_cast<const float4*>(in)[(size_t)c * F4 + j];
    }
    if (SCALE_SRC) {
      float sc = sSrc[c];
      v.x *= sc; v.y *= sc; v.z *= sc; v.w *= sc;
    }
    acc.x += v.x; acc.y += v.y; acc.z += v.z; acc.w += v.w;
  }
  if (EPI == 0) {
    if (OUT_BF) {
      ushort4 p;
      p.x = f2bf(acc.x); p.y = f2bf(acc.y); p.z = f2bf(acc.z); p.w = f2bf(acc.w);
      nt_store_u4(p, (unsigned short*)out + (size_t)node * F + j * 4);
    } else {
      nt_store_f4(acc, (float*)out + (size_t)node * F + j * 4);
    }
    return;
  }
  float sd = sDst[node];
  float4 bb = reinterpret_cast<const float4*>(bias)[j];
  acc.x = acc.x * sd + bb.x;
  acc.y = acc.y * sd + bb.y;
  acc.z = acc.z * sd + bb.z;
  acc.w = acc.w * sd + bb.w;
  if (EPI == 1) {
    if (OUT_BF) {
      ushort4 p;
      p.x = f2bf(acc.x); p.y = f2bf(acc.y); p.z = f2bf(acc.z); p.w = f2bf(acc.w);
      nt_store_u4(p, (unsigned short*)out + (size_t)node * F + j * 4);
    } else {
      nt_store_f4(acc, (float*)out + (size_t)node * F + j * 4);
    }
  }
  float4 o;
  o.x = 1.0f / (1.0f + expf(-acc.x));
  o.y = 1.0f / (1.0f + expf(-acc.y));
  o.z = 1.0f / (1.0f + expf(-acc.z));
  o.w = 1.0f / (1.0f + expf(-acc.w));
  nt_store_f4(o, out2 + (size_t)node * F + j * 4);
}

// ---------------- gemm6: skinny-K GEMM (K=KT*32 <= 256), A-band held in registers ----
// C[M rows][Nreal] bf16 = relu(rowscale[r]*(A[band] @ Bt^T) + bias), nt-stored.
// Block = 4 waves; wave w owns band mb*4+w (64 rows), n-tile nt (64 cols of Npad=NTn*64).
// A 64xK held in VGPR (KT*4 bf16x8). B streamed with named 2-deep ping-pong ->
// compiler keeps counted vmcnt, no barriers, no LDS. nt C-stores protect L2 (A reuse).
template <int KT, int RELU>
__global__ __launch_bounds__(256) void gemm6_kernel(
    const unsigned short* __restrict__ A, const unsigned short* __restrict__ Bt,
    unsigned short* __restrict__ C, int M, int Nreal, int NTn,
    const float* __restrict__ rowscale, const float* __restrict__ bias) {
  constexpr int K = KT * 32;
  const int sw = xcd_swizzle(blockIdx.x, gridDim.x);
  const int mb = sw / NTn, nt = sw - mb * NTn;  // n-fastest: same XCD covers contiguous m
  const int l = threadIdx.x & 63, w = threadIdx.x >> 6;
  const int lrow = l & 15, k16 = l >> 4;
  const int m0 = (mb * 4 + w) * 64, n0 = nt * 64;
  const unsigned short* ap = A + (size_t)(m0 + lrow) * K + k16 * 8;
  const unsigned short* bp = Bt + (size_t)(n0 + lrow) * K + k16 * 8;

  // ---- hold A band (64 x K) in registers ----
  bf16x8 ar[KT][4];
#pragma unroll
  for (int t = 0; t < KT; ++t)
#pragma unroll
    for (int mi = 0; mi < 4; ++mi)
      ar[t][mi] = *reinterpret_cast<const bf16x8*>(ap + (size_t)mi * 16 * K + t * 32);

  f32x4 acc[4][4] = {};
  bf16x8 b0[4], b1[4];

#define LB6(dst, t)                                                                  \
  _Pragma("unroll") for (int ni = 0; ni < 4; ++ni)                                   \
      dst[ni] = *reinterpret_cast<const bf16x8*>(bp + (size_t)ni * 16 * K + (t) * 32);
#define MM6(bb, t)                                                                   \
  _Pragma("unroll") for (int mi = 0; mi < 4; ++mi)                                   \
      _Pragma("unroll") for (int ni = 0; ni < 4; ++ni)                               \
          acc[mi][ni] = __builtin_amdgcn_mfma_f32_16x16x32_bf16(ar[t][mi], bb[ni], acc[mi][ni], 0, 0, 0);

  LB6(b0, 0)
#pragma unroll
  for (int tt = 0; tt <= KT / 2 - 2; ++tt) {
    LB6(b1, 2 * tt + 1)
    MM6(b0, 2 * tt)
    LB6(b0, 2 * tt + 2)
    MM6(b1, 2 * tt + 1)
  }
  LB6(b1, KT - 1)
  MM6(b0, KT - 2)
  MM6(b1, KT - 1)
#undef LB6
#undef MM6

  // ---- epilogue: nt scalar stores (C row stride = Nreal) ----
#pragma unroll
  for (int mi = 0; mi < 4; ++mi) {
#pragma unroll
    for (int q = 0; q < 4; ++q) {
      int r = m0 + mi * 16 + k16 * 4 + q;
      if (r >= M) continue;
      float rs = rowscale[r];
#pragma unroll
      for (int ni = 0; ni < 4; ++ni) {
        int c = n0 + ni * 16 + lrow;
        if (c >= Nreal) continue;
        float v = acc[mi][ni][q] * rs + bias[c];
        if (RELU) v = fmaxf(v, 0.f);
        __builtin_nontemporal_store(f2bf(v), &C[(size_t)r * Nreal + c]);
      }
    }
  }
}

// ---------------- gemm7: K=800 GEMM, 32x32 per-wave tiles, 2-deep dbuf ----------------
// C[M][N] = rowscale[r] * (A[MH][800] @ Bt[N][800]^T); N = NTI*32; OUT_BF selects bf16/f32.
// Block = 4 waves; flat tile = sw*4 + w, n-fastest (A-band reuse within/between blocks).
// nt C-stores.
template <int NTI, int OUT_BF>
__global__ __launch_bounds__(256) void gemm7_kernel(
    const unsigned short* __restrict__ A, const unsigned short* __restrict__ Bt,
    void* __restrict__ C, int M, const float* __restrict__ rowscale) {
  constexpr int K = 800, N = NTI * 32;
  const int sw = xcd_swizzle(blockIdx.x, gridDim.x);
  const int tile = sw * 4 + (threadIdx.x >> 6);
  const int mt = tile / NTI, nt = tile - mt * NTI;
  const int l = threadIdx.x & 63;
  const int lrow = l & 15, k16 = l >> 4;
  const int m0 = mt * 32, n0 = nt * 32;
  const unsigned short* ap = A + (size_t)(m0 + lrow) * K + k16 * 8;
  const unsigned short* bp = Bt + (size_t)(n0 + lrow) * K + k16 * 8;

  f32x4 acc[2][2] = {};
  bf16x8 a0[2], b0[2], a1[2], b1[2];

#define LAB7(aa, bb, t)                                                                \
  _Pragma("unroll") for (int i = 0; i < 2; ++i) {                                      \
    aa[i] = *reinterpret_cast<const bf16x8*>(ap + (size_t)i * 16 * K + (t) * 32);      \
    bb[i] = *reinterpret_cast<const bf16x8*>(bp + (size_t)i * 16 * K + (t) * 32);      \
  }
#define MM7(aa, bb)                                                                    \
  _Pragma("unroll") for (int mi = 0; mi < 2; ++mi)                                     \
      _Pragma("unroll") for (int ni = 0; ni < 2; ++ni)                                 \
          acc[mi][ni] = __builtin_amdgcn_mfma_f32_16x16x32_bf16(aa[mi], bb[ni], acc[mi][ni], 0, 0, 0);

  LAB7(a0, b0, 0)
#pragma unroll
  for (int tt = 0; tt < 12; ++tt) {  // covers t = 0..23; t=24 computed after loop
    LAB7(a1, b1, 2 * tt + 1)
    MM7(a0, b0)
    LAB7(a0, b0, 2 * tt + 2)
    MM7(a1, b1)
  }
  MM7(a0, b0)  // t = 24
#undef LAB7
#undef MM7

#pragma unroll
  for (int mi = 0; mi < 2; ++mi) {
#pragma unroll
    for (int q = 0; q < 4; ++q) {
      int r = m0 + mi * 16 + k16 * 4 + q;
      if (r >= M) continue;
      float rs = rowscale[r];
#pragma unroll
      for (int ni = 0; ni < 2; ++ni) {
        int c = n0 + ni * 16 + lrow;
        float v = acc[mi][ni][q] * rs;
        if (OUT_BF) __builtin_nontemporal_store(f2bf(v), &((unsigned short*)C)[(size_t)r * N + c]);
        else __builtin_nontemporal_store(v, &((float*)C)[(size_t)r * N + c]);
      }
    }
  }
}

extern "C" void kernel_launch(void* const* d_in, const int* in_sizes, int n_in,
                              void* d_out, int out_size, void* d_ws, size_t ws_size,
                              hipStream_t stream) {
  const float* x  = (const float*)d_in[0];
  const int* src  = (const int*)d_in[1];
  const int* dst  = (const int*)d_in[2];
  const float* W1 = (const float*)d_in[3];
  const float* b1 = (const float*)d_in[4];
  const float* W2 = (const float*)d_in[5];
  const float* b2 = (const float*)d_in[6];
  const float* W3 = (const float*)d_in[7];
  const float* b3 = (const float*)d_in[8];
  const float* W4 = (const float*)d_in[9];
  const float* b4 = (const float*)d_in[10];

  float* out_enc = (float*)d_out;                  // [NN,128]
  float* out_dec = out_enc + (size_t)NN * 128;     // [NN,256]

  // ---- workspace layout (~77 MB) ----
  float* ns = (float*)d_ws;                        // [NN]
  float* nd = ns + NN;                             // [NN]
  float* T2 = nd + NN;                             // [NN*128] f32   (gemm7-L2 out)
  unsigned short* h2  = (unsigned short*)(T2 + (size_t)NN * 128); // [NN*128] bf16
  unsigned short* A1  = h2 + (size_t)NN * 128;     // [MROWS*256] bf16
  unsigned short* A3  = A1 + (size_t)MROWS * 256;  // [MROWS*128] bf16
  unsigned short* G4  = A3 + (size_t)MROWS * 128;  // [NN*256] bf16 (gemm7-L4 out)
  unsigned short* H1  = G4 + (size_t)NN * 256;     // [MH*800] bf16 (gemm6 out)
  unsigned short* W1t = H1 + (size_t)MH * 800;     // [832*256]
  unsigned short* W2t = W1t + 832 * 256;           // [128*800]
  unsigned short* W3t = W2t + 128 * 800;           // [832*128]
  unsigned short* W4t = W3t + 832 * 128;           // [256*800]
  int* degs   = (int*)(W4t + 256 * 800);           // [NN]
  int* degd   = degs + NN;                         // [NN]
  int* cursor = degd + NN;                         // [NN]
  int* rowptr = cursor + NN;                       // [NN+1]
  int* col    = rowptr + NN + 1;                   // [NE]

  // ---- CSR build + norms ----
  (void)hipMemsetAsync(degs, 0, 3 * NN * sizeof(int), stream);
  deg_count_kernel<<<(NE + 255) / 256, 256, 0, stream>>>(src, dst, degs, degd, NE);
  norm_kernel<<<(NN + 255) / 256, 256, 0, stream>>>(degs, degd, ns, nd, NN);
  scan_kernel<<<1, 1024, 0, stream>>>(degd, rowptr, NN);
  csr_fill_kernel<<<(NE + 255) / 256, 256, 0, stream>>>(src, dst, rowptr, cursor, col, NE);

  // ---- weight conversion: Wt[Npad][Kpad] bf16 ----
  wt_convert_kernel<<<dim3(1, 832), 256, 0, stream>>>(W1, W1t, 256, 800, 256);
  wt_convert_kernel<<<dim3(4, 128), 256, 0, stream>>>(W2, W2t, 800, 128, 800);
  wt_convert_kernel<<<dim3(1, 832), 256, 0, stream>>>(W3, W3t, 128, 800, 128);
  wt_convert_kernel<<<dim3(4, 256), 256, 0, stream>>>(W4, W4t, 800, 256, 800);

  // grids: gemm6: 316 bands / 4 waves = 79 m-blocks x 13 n-tiles (Npad 832)
  const int G6 = 79 * 13;
  // gemm7: L2: 628 mt x 4 nt / 4 waves = 628 blocks; L4: 628 x 8 / 4 = 1256
  const int G7L2 = 628, G7L4 = 1256;

  // ---- L1: gather(x*ns) -> bf16 A1; gemm6 (K=256 -> 800) relu -> H1 ----
  gather_kernel<256, 1, 0, 1, 0><<<(NN + 3) / 4, 256, 0, stream>>>(
      x, ns, rowptr, col, nullptr, nullptr, A1, nullptr, NN);
  gemm6_kernel<8, 1><<<G6, 256, 0, stream>>>(A1, W1t, H1, NN, 800, 13, nd, b1);

  // ---- L2: gemm7 (800 -> 128)*ns -> f32 T2; gather -> bf16 h2 + sigmoid(out_enc) ----
  gemm7_kernel<4, 0><<<G7L2, 256, 0, stream>>>(H1, W2t, T2, NN, ns);
  gather_kernel<128, 0, 1, 1, 0><<<(NN + 7) / 8, 256, 0, stream>>>(
      T2, nullptr, rowptr, col, nd, b2, h2, out_enc, NN);

  // ---- L3: gather(h2*ns) -> bf16 A3; gemm6 (K=128 -> 800) relu -> H1 ----
  gather_kernel<128, 1, 0, 1, 1><<<(NN + 7) / 8, 256, 0, stream>>>(
      h2, ns, rowptr, col, nullptr, nullptr, A3, nullptr, NN);
  gemm6_kernel<4, 1><<<G6, 256, 0, stream>>>(A3, W3t, H1, NN, 800, 13, nd, b3);

  // ---- L4: gemm7 (800 -> 256)*ns -> bf16 G4; gather -> sigmoid(out_dec) ----
  gemm7_kernel<8, 1><<<G7L4, 256, 0, stream>>>(H1, W4t, G4, NN, ns);
  gather_kernel<256, 0, 2, 0, 1><<<(NN + 3) / 4, 256, 0, stream>>>(
      G4, nullptr, rowptr, col, nd, b4, nullptr, out_dec, NN);
}

// Round 10
// 336.006 us; speedup vs baseline: 1.3943x; 1.2914x over previous
//
#include <hip/hip_runtime.h>
#include <math.h>

constexpr int NN = 20000;   // nodes
constexpr int NE = 320000;  // edges
constexpr int MROWS = 20224; // A1/A3 row padding
constexpr int MH = 20096;   // H1 rows (157 groups of 128)

typedef __bf16 bf16x8 __attribute__((ext_vector_type(8)));
typedef float f32x4 __attribute__((ext_vector_type(4)));

__device__ __forceinline__ unsigned short f2bf(float f) {
  unsigned int u = __float_as_uint(f);
  unsigned int r = (u + 0x7FFFu + ((u >> 16) & 1u)) >> 16;
  return (unsigned short)r;
}
__device__ __forceinline__ float bf2f(unsigned short s) {
  return __uint_as_float(((unsigned int)s) << 16);
}

// bijective XCD chunking (m204)
__device__ __forceinline__ int xcd_swizzle(int bid, int T) {
  int q = T >> 3, r = T & 7;
  int x = bid & 7, i = bid >> 3;
  return (x < r ? x * (q + 1) : r * (q + 1) + (x - r) * q) + i;
}

// ---------------- degree count ----------------
__global__ void deg_count_kernel(const int* __restrict__ src, const int* __restrict__ dst,
                                 int* __restrict__ degs, int* __restrict__ degd, int nE) {
  int e = blockIdx.x * blockDim.x + threadIdx.x;
  if (e < nE) {
    atomicAdd(degs + src[e], 1);
    atomicAdd(degd + dst[e], 1);
  }
}

__global__ void norm_kernel(const int* __restrict__ degs, const int* __restrict__ degd,
                            float* __restrict__ ns, float* __restrict__ nd, int n) {
  int i = blockIdx.x * blockDim.x + threadIdx.x;
  if (i < n) {
    ns[i] = rsqrtf(fmaxf((float)degs[i], 1.0f));
    nd[i] = rsqrtf(fmaxf((float)degd[i], 1.0f));
  }
}

// ---------------- single-block exclusive scan -> rowptr ----------------
__global__ __launch_bounds__(1024) void scan_kernel(const int* __restrict__ deg,
                                                    int* __restrict__ rowptr, int n) {
  constexpr int T = 1024;
  const int ITEMS = (n + T - 1) / T;
  __shared__ int sums[T];
  int t = threadIdx.x;
  int base = t * ITEMS;
  int s = 0;
  for (int i = 0; i < ITEMS; ++i) {
    int idx = base + i;
    if (idx < n) s += deg[idx];
  }
  sums[t] = s;
  __syncthreads();
  for (int off = 1; off < T; off <<= 1) {
    int v = (t >= off) ? sums[t - off] : 0;
    __syncthreads();
    sums[t] += v;
    __syncthreads();
  }
  int ex = (t == 0) ? 0 : sums[t - 1];
  for (int i = 0; i < ITEMS; ++i) {
    int idx = base + i;
    if (idx < n) {
      rowptr[idx] = ex;
      ex += deg[idx];
    }
  }
  if (t == 0) rowptr[n] = sums[T - 1];
}

// ---------------- CSR fill ----------------
__global__ void csr_fill_kernel(const int* __restrict__ src, const int* __restrict__ dst,
                                const int* __restrict__ rowptr, int* __restrict__ cursor,
                                int* __restrict__ col, int nE) {
  int e = blockIdx.x * blockDim.x + threadIdx.x;
  if (e < nE) {
    int d = dst[e];
    int p = atomicAdd(cursor + d, 1);
    col[rowptr[d] + p] = src[e];
  }
}

// ---------------- weight convert: W[K][N] f32 -> Wt[Npad][Kpad] bf16 (zero pad) -------
__global__ void wt_convert_kernel(const float* __restrict__ W, unsigned short* __restrict__ Wt,
                                  int K, int N, int Kpad) {
  int k = blockIdx.x * 256 + threadIdx.x;
  int n = blockIdx.y;
  if (k >= Kpad) return;
  float v = (n < N && k < K) ? W[(size_t)k * N + n] : 0.f;
  Wt[(size_t)n * Kpad + k] = f2bf(v);
}

// ---------------- CSR gather aggregation (plain stores; r6-proven) ----------------
// EPI==0: raw sum -> out. EPI==1: v=sum*sDst+b -> out AND sigmoid(v)->out2.
// EPI==2: v=sum*sDst+b -> sigmoid(v)->out2 only.
template <int F, int SCALE_SRC, int EPI, int OUT_BF, int IN_BF>
__global__ __launch_bounds__(256) void gather_kernel(
    const void* __restrict__ in, const float* __restrict__ sSrc,
    const int* __restrict__ rowptr, const int* __restrict__ col,
    const float* __restrict__ sDst, const float* __restrict__ bias,
    void* __restrict__ out, float* __restrict__ out2, int n) {
  constexpr int F4 = F / 4;
  constexpr int NPB = 256 / F4;
  int tid = threadIdx.x;
  int node = blockIdx.x * NPB + tid / F4;
  int j = tid % F4;
  if (node >= n) return;
  int e0 = rowptr[node], e1 = rowptr[node + 1];
  float4 acc = make_float4(0.f, 0.f, 0.f, 0.f);
  for (int e = e0; e < e1; ++e) {
    int c = col[e];
    float4 v;
    if (IN_BF) {
      ushort4 u = reinterpret_cast<const ushort4*>(in)[(size_t)c * F4 + j];
      v = make_float4(bf2f(u.x), bf2f(u.y), bf2f(u.z), bf2f(u.w));
    } else {
      v = reinterpret_cast<const float4*>(in)[(size_t)c * F4 + j];
    }
    if (SCALE_SRC) {
      float sc = sSrc[c];
      v.x *= sc; v.y *= sc; v.z *= sc; v.w *= sc;
    }
    acc.x += v.x; acc.y += v.y; acc.z += v.z; acc.w += v.w;
  }
  if (EPI == 0) {
    if (OUT_BF) {
      ushort4 p;
      p.x = f2bf(acc.x); p.y = f2bf(acc.y); p.z = f2bf(acc.z); p.w = f2bf(acc.w);
      reinterpret_cast<ushort4*>(out)[(size_t)node * F4 + j] = p;
    } else {
      reinterpret_cast<float4*>(out)[(size_t)node * F4 + j] = acc;
    }
    return;
  }
  float sd = sDst[node];
  float4 bb = reinterpret_cast<const float4*>(bias)[j];
  acc.x = acc.x * sd + bb.x;
  acc.y = acc.y * sd + bb.y;
  acc.z = acc.z * sd + bb.z;
  acc.w = acc.w * sd + bb.w;
  if (EPI == 1) {
    if (OUT_BF) {
      ushort4 p;
      p.x = f2bf(acc.x); p.y = f2bf(acc.y); p.z = f2bf(acc.z); p.w = f2bf(acc.w);
      reinterpret_cast<ushort4*>(out)[(size_t)node * F4 + j] = p;
    } else {
      reinterpret_cast<float4*>(out)[(size_t)node * F4 + j] = acc;
    }
  }
  float4 o;
  o.x = 1.0f / (1.0f + expf(-acc.x));
  o.y = 1.0f / (1.0f + expf(-acc.y));
  o.z = 1.0f / (1.0f + expf(-acc.z));
  o.w = 1.0f / (1.0f + expf(-acc.w));
  reinterpret_cast<float4*>(out2)[(size_t)node * F4 + j] = o;
}

// ================= gemm8s: small-K GEMM (K = KT*32, Kpad==K, KT<=8) ===============
// C[M][Nreal] bf16 = relu(nd[r]*(A @ Bt^T) + bias). Block = 4 waves; block tile
// 128 rows x 64 cols (wave = 32 x 64). WHOLE B n-tile [64xK] staged to LDS once
// (global_load_lds w16, XOR-swizzled source; read with same XOR -> conflict-free).
// ALL per-wave A-frags (KT*2, <=16) issued before the single barrier. After the
// barrier: pure ds_read+MFMA burst -- zero inner barriers, zero global latency.
template <int KT, int RELU>
__global__ __launch_bounds__(256) void gemm8s_kernel(
    const unsigned short* __restrict__ A, const unsigned short* __restrict__ Bt,
    unsigned short* __restrict__ C, int M, int Nreal, int NTn,
    const float* __restrict__ rowscale, const float* __restrict__ bias) {
  constexpr int K = KT * 32;
  constexpr int CPR = KT * 4;            // 16B chunks per LDS row
  constexpr int ROWB = CPR * 16;
  constexpr int TC = 64 * CPR;           // total chunks
  __shared__ __align__(16) char lds[64 * ROWB];

  const int sw = xcd_swizzle(blockIdx.x, gridDim.x);
  const int mg = sw / NTn, nt = sw - mg * NTn;  // n-fastest within XCD chunk
  const int tid = threadIdx.x;
  const int l = tid & 63, w = tid >> 6;
  const int lrow = l & 15, k16 = l >> 4;
  const int m0 = mg * 128 + w * 32, n0 = nt * 64;

  // ---- stage B[64][K] -> LDS (linear dest, inverse-swizzled source) ----
#pragma unroll
  for (int i = 0; i < TC / 256; ++i) {
    int c = i * 256 + tid;
    int row = c / CPR, lch = c % CPR;
    int gch = (lch & ~7) | ((lch & 7) ^ (row & 7));
    const unsigned short* gp = Bt + (size_t)(n0 + row) * K + gch * 8;
    __builtin_amdgcn_global_load_lds(
        (const __attribute__((address_space(1))) void*)gp,
        (__attribute__((address_space(3))) void*)(lds + (i * 256 + w * 64) * 16), 16, 0, 0);
  }

  // ---- issue ALL A-frags (independent of LDS) ----
  bf16x8 af[KT][2];
#pragma unroll
  for (int t = 0; t < KT; ++t)
#pragma unroll
    for (int mi = 0; mi < 2; ++mi)
      af[t][mi] = *reinterpret_cast<const bf16x8*>(
          A + (size_t)(m0 + mi * 16 + lrow) * K + t * 32 + k16 * 8);

  __syncthreads();  // single barrier: drains staging (and A-frags)

  // ---- pure LDS + MFMA burst ----
  f32x4 acc[2][4] = {};
#pragma unroll
  for (int t = 0; t < KT; ++t) {
    bf16x8 bf[4];
#pragma unroll
    for (int ni = 0; ni < 4; ++ni) {
      int row = ni * 16 + lrow;
      int ch = t * 4 + k16;
      int sc = (ch & ~7) | ((ch & 7) ^ (row & 7));
      bf[ni] = *reinterpret_cast<const bf16x8*>(lds + row * ROWB + sc * 16);
    }
#pragma unroll
    for (int mi = 0; mi < 2; ++mi)
#pragma unroll
      for (int ni = 0; ni < 4; ++ni)
        acc[mi][ni] = __builtin_amdgcn_mfma_f32_16x16x32_bf16(af[t][mi], bf[ni], acc[mi][ni], 0, 0, 0);
  }

  // ---- epilogue (plain stores; L2 coalesces) ----
#pragma unroll
  for (int mi = 0; mi < 2; ++mi) {
#pragma unroll
    for (int q = 0; q < 4; ++q) {
      int r = m0 + mi * 16 + k16 * 4 + q;
      if (r >= M) continue;
      float rs = rowscale[r];
#pragma unroll
      for (int ni = 0; ni < 4; ++ni) {
        int c = n0 + ni * 16 + lrow;
        if (c >= Nreal) continue;
        float v = acc[mi][ni][q] * rs + bias[c];
        if (RELU) v = fmaxf(v, 0.f);
        C[(size_t)r * Nreal + c] = f2bf(v);
      }
    }
  }
}

// ================= gemm8l: K=800 GEMM, B-tile staged in 2 LDS phases ===============
// C[M][N] = ns[r] * (A[MH][800] @ Bt[N][800]^T); Bt Kpad=832 (zero-fill).
// Block = 4 waves, tile 128 x 64. LDS = 64 rows x 52 chunks (52 KB), XOR mask 3.
// Phase p stages chunks [p*52, p*52+52) (cols p*416..), computes t-range; 3 barriers
// total per block, no per-k-step sync. A-frags loaded inline (short live ranges).
template <int OUT_BF>
__global__ __launch_bounds__(256) void gemm8l_kernel(
    const unsigned short* __restrict__ A, const unsigned short* __restrict__ Bt,
    void* __restrict__ C, int M, int N, int NTn,
    const float* __restrict__ rowscale) {
  constexpr int K = 800, KPAD = 832;
  constexpr int CPR = 52;               // chunks per row per phase
  constexpr int ROWB = CPR * 16;
  __shared__ __align__(16) char lds[64 * ROWB];  // 52 KB

  const int sw = xcd_swizzle(blockIdx.x, gridDim.x);
  const int mg = sw / NTn, nt = sw - mg * NTn;
  const int tid = threadIdx.x;
  const int l = tid & 63, w = tid >> 6;
  const int lrow = l & 15, k16 = l >> 4;
  const int m0 = mg * 128 + w * 32, n0 = nt * 64;

  auto stage = [&](int phase) {
#pragma unroll
    for (int i = 0; i < 13; ++i) {  // 64*52/256
      int c = i * 256 + tid;
      int row = c / CPR, lch = c % CPR;
      int gch = phase * CPR + ((lch & ~3) | ((lch & 3) ^ (row & 3)));
      const unsigned short* gp = Bt + (size_t)(n0 + row) * KPAD + gch * 8;
      __builtin_amdgcn_global_load_lds(
          (const __attribute__((address_space(1))) void*)gp,
          (__attribute__((address_space(3))) void*)(lds + (i * 256 + w * 64) * 16), 16, 0, 0);
    }
  };

  f32x4 acc[2][4] = {};

  auto compute = [&](int t0, int t1, int phase) {
#pragma unroll 13
    for (int t = t0; t < t1; ++t) {
      bf16x8 a[2];
#pragma unroll
      for (int mi = 0; mi < 2; ++mi)
        a[mi] = *reinterpret_cast<const bf16x8*>(
            A + (size_t)(m0 + mi * 16 + lrow) * K + t * 32 + k16 * 8);
      bf16x8 bf[4];
#pragma unroll
      for (int ni = 0; ni < 4; ++ni) {
        int row = ni * 16 + lrow;
        int ch = t * 4 + k16 - phase * CPR;
        int sc = (ch & ~3) | ((ch & 3) ^ (row & 3));
        bf[ni] = *reinterpret_cast<const bf16x8*>(lds + row * ROWB + sc * 16);
      }
#pragma unroll
      for (int mi = 0; mi < 2; ++mi)
#pragma unroll
        for (int ni = 0; ni < 4; ++ni)
          acc[mi][ni] = __builtin_amdgcn_mfma_f32_16x16x32_bf16(a[mi], bf[ni], acc[mi][ni], 0, 0, 0);
    }
  };

  stage(0);
  __syncthreads();
  compute(0, 13, 0);      // chunks 0..51
  __syncthreads();        // all waves done with phase-0 LDS
  stage(1);
  __syncthreads();
  compute(13, 25, 1);     // chunks 52..99 (local 0..47)

#pragma unroll
  for (int mi = 0; mi < 2; ++mi) {
#pragma unroll
    for (int q = 0; q < 4; ++q) {
      int r = m0 + mi * 16 + k16 * 4 + q;
      if (r >= M) continue;
      float rs = rowscale[r];
#pragma unroll
      for (int ni = 0; ni < 4; ++ni) {
        int c = n0 + ni * 16 + lrow;
        float v = acc[mi][ni][q] * rs;
        if (OUT_BF) ((unsigned short*)C)[(size_t)r * N + c] = f2bf(v);
        else ((float*)C)[(size_t)r * N + c] = v;
      }
    }
  }
}

extern "C" void kernel_launch(void* const* d_in, const int* in_sizes, int n_in,
                              void* d_out, int out_size, void* d_ws, size_t ws_size,
                              hipStream_t stream) {
  const float* x  = (const float*)d_in[0];
  const int* src  = (const int*)d_in[1];
  const int* dst  = (const int*)d_in[2];
  const float* W1 = (const float*)d_in[3];
  const float* b1 = (const float*)d_in[4];
  const float* W2 = (const float*)d_in[5];
  const float* b2 = (const float*)d_in[6];
  const float* W3 = (const float*)d_in[7];
  const float* b3 = (const float*)d_in[8];
  const float* W4 = (const float*)d_in[9];
  const float* b4 = (const float*)d_in[10];

  float* out_enc = (float*)d_out;                  // [NN,128]
  float* out_dec = out_enc + (size_t)NN * 128;     // [NN,256]

  // ---- workspace layout (~78 MB) ----
  float* ns = (float*)d_ws;                        // [NN]
  float* nd = ns + NN;                             // [NN]
  float* T2 = nd + NN;                             // [NN*128] f32 (gemm8l-L2 out)
  unsigned short* h2  = (unsigned short*)(T2 + (size_t)NN * 128); // [NN*128] bf16
  unsigned short* A1  = h2 + (size_t)NN * 128;     // [MROWS*256]
  unsigned short* A3  = A1 + (size_t)MROWS * 256;  // [MROWS*128]
  unsigned short* G4  = A3 + (size_t)MROWS * 128;  // [NN*256] bf16 (gemm8l-L4 out)
  unsigned short* H1  = G4 + (size_t)NN * 256;     // [MH*800] bf16 (gemm8s out)
  unsigned short* W1t = H1 + (size_t)MH * 800;     // [832*256]
  unsigned short* W2t = W1t + 832 * 256;           // [128*832]
  unsigned short* W3t = W2t + 128 * 832;           // [832*128]
  unsigned short* W4t = W3t + 832 * 128;           // [256*832]
  int* degs   = (int*)(W4t + 256 * 832);           // [NN]
  int* degd   = degs + NN;                         // [NN]
  int* cursor = degd + NN;                         // [NN]
  int* rowptr = cursor + NN;                       // [NN+1]
  int* col    = rowptr + NN + 1;                   // [NE]

  // ---- CSR build + norms ----
  (void)hipMemsetAsync(degs, 0, 3 * NN * sizeof(int), stream);
  deg_count_kernel<<<(NE + 255) / 256, 256, 0, stream>>>(src, dst, degs, degd, NE);
  norm_kernel<<<(NN + 255) / 256, 256, 0, stream>>>(degs, degd, ns, nd, NN);
  scan_kernel<<<1, 1024, 0, stream>>>(degd, rowptr, NN);
  csr_fill_kernel<<<(NE + 255) / 256, 256, 0, stream>>>(src, dst, rowptr, cursor, col, NE);

  // ---- weight conversion: Wt[Npad][Kpad] bf16 ----
  wt_convert_kernel<<<dim3(1, 832), 256, 0, stream>>>(W1, W1t, 256, 800, 256);
  wt_convert_kernel<<<dim3(4, 128), 256, 0, stream>>>(W2, W2t, 800, 128, 832);
  wt_convert_kernel<<<dim3(1, 832), 256, 0, stream>>>(W3, W3t, 128, 800, 128);
  wt_convert_kernel<<<dim3(4, 256), 256, 0, stream>>>(W4, W4t, 800, 256, 832);

  // grids: 157 m-groups of 128 rows; n-tiles of 64
  const int GS = 157 * 13;   // gemm8s L1/L3 (Npad 832)
  const int GL2 = 157 * 2;   // gemm8l L2 (N=128)
  const int GL4 = 157 * 4;   // gemm8l L4 (N=256)

  // ---- L1: gather(x*ns) -> bf16 A1; gemm8s (K=256 -> 800) relu -> H1 ----
  gather_kernel<256, 1, 0, 1, 0><<<(NN + 3) / 4, 256, 0, stream>>>(
      x, ns, rowptr, col, nullptr, nullptr, A1, nullptr, NN);
  gemm8s_kernel<8, 1><<<GS, 256, 0, stream>>>(A1, W1t, H1, NN, 800, 13, nd, b1);

  // ---- L2: gemm8l (800 -> 128)*ns -> f32 T2; gather -> bf16 h2 + sigmoid(out_enc) ----
  gemm8l_kernel<0><<<GL2, 256, 0, stream>>>(H1, W2t, T2, NN, 128, 2, ns);
  gather_kernel<128, 0, 1, 1, 0><<<(NN + 7) / 8, 256, 0, stream>>>(
      T2, nullptr, rowptr, col, nd, b2, h2, out_enc, NN);

  // ---- L3: gather(h2*ns) -> bf16 A3; gemm8s (K=128 -> 800) relu -> H1 ----
  gather_kernel<128, 1, 0, 1, 1><<<(NN + 7) / 8, 256, 0, stream>>>(
      h2, ns, rowptr, col, nullptr, nullptr, A3, nullptr, NN);
  gemm8s_kernel<4, 1><<<GS, 256, 0, stream>>>(A3, W3t, H1, NN, 800, 13, nd, b3);

  // ---- L4: gemm8l (800 -> 256)*ns -> bf16 G4; gather -> sigmoid(out_dec) ----
  gemm8l_kernel<1><<<GL4, 256, 0, stream>>>(H1, W4t, G4, NN, 256, 4, ns);
  gather_kernel<256, 0, 2, 0, 1><<<(NN + 3) / 4, 256, 0, stream>>>(
      G4, nullptr, rowptr, col, nd, b4, nullptr, out_dec, NN);
}

// Round 11
// 301.940 us; speedup vs baseline: 1.5516x; 1.1128x over previous
//
#include <hip/hip_runtime.h>
#include <math.h>

constexpr int NN = 20000;   // nodes
constexpr int NE = 320000;  // edges
constexpr int MROWS = 20224; // A1/A3 row padding
constexpr int MH = 20096;   // H1 rows (157 groups of 128)

typedef __bf16 bf16x8 __attribute__((ext_vector_type(8)));
typedef float f32x4 __attribute__((ext_vector_type(4)));

__device__ __forceinline__ unsigned short f2bf(float f) {
  unsigned int u = __float_as_uint(f);
  unsigned int r = (u + 0x7FFFu + ((u >> 16) & 1u)) >> 16;
  return (unsigned short)r;
}

// bijective XCD chunking (m204)
__device__ __forceinline__ int xcd_swizzle(int bid, int T) {
  int q = T >> 3, r = T & 7;
  int x = bid & 7, i = bid >> 3;
  return (x < r ? x * (q + 1) : r * (q + 1) + (x - r) * q) + i;
}

// ---------------- degree count ----------------
__global__ void deg_count_kernel(const int* __restrict__ src, const int* __restrict__ dst,
                                 int* __restrict__ degs, int* __restrict__ degd, int nE) {
  int e = blockIdx.x * blockDim.x + threadIdx.x;
  if (e < nE) {
    atomicAdd(degs + src[e], 1);
    atomicAdd(degd + dst[e], 1);
  }
}

__global__ void norm_kernel(const int* __restrict__ degs, const int* __restrict__ degd,
                            float* __restrict__ ns, float* __restrict__ nd, int n) {
  int i = blockIdx.x * blockDim.x + threadIdx.x;
  if (i < n) {
    ns[i] = rsqrtf(fmaxf((float)degs[i], 1.0f));
    nd[i] = rsqrtf(fmaxf((float)degd[i], 1.0f));
  }
}

// ---------------- single-block exclusive scan -> rowptr ----------------
__global__ __launch_bounds__(1024) void scan_kernel(const int* __restrict__ deg,
                                                    int* __restrict__ rowptr, int n) {
  constexpr int T = 1024;
  const int ITEMS = (n + T - 1) / T;
  __shared__ int sums[T];
  int t = threadIdx.x;
  int base = t * ITEMS;
  int s = 0;
  for (int i = 0; i < ITEMS; ++i) {
    int idx = base + i;
    if (idx < n) s += deg[idx];
  }
  sums[t] = s;
  __syncthreads();
  for (int off = 1; off < T; off <<= 1) {
    int v = (t >= off) ? sums[t - off] : 0;
    __syncthreads();
    sums[t] += v;
    __syncthreads();
  }
  int ex = (t == 0) ? 0 : sums[t - 1];
  for (int i = 0; i < ITEMS; ++i) {
    int idx = base + i;
    if (idx < n) {
      rowptr[idx] = ex;
      ex += deg[idx];
    }
  }
  if (t == 0) rowptr[n] = sums[T - 1];
}

// ---------------- CSR fill ----------------
__global__ void csr_fill_kernel(const int* __restrict__ src, const int* __restrict__ dst,
                                const int* __restrict__ rowptr, int* __restrict__ cursor,
                                int* __restrict__ col, int nE) {
  int e = blockIdx.x * blockDim.x + threadIdx.x;
  if (e < nE) {
    int d = dst[e];
    int p = atomicAdd(cursor + d, 1);
    col[rowptr[d] + p] = src[e];
  }
}

// ---------------- weight convert: W[K][N] f32 -> Wt[Npad][Kpad] bf16 (zero pad) -------
__global__ void wt_convert_kernel(const float* __restrict__ W, unsigned short* __restrict__ Wt,
                                  int K, int N, int Kpad) {
  int k = blockIdx.x * 256 + threadIdx.x;
  int n = blockIdx.y;
  if (k >= Kpad) return;
  float v = (n < N && k < K) ? W[(size_t)k * N + n] : 0.f;
  Wt[(size_t)n * Kpad + k] = f2bf(v);
}

// ---------------- xb = bf16(x * ns[row]) pre-pass (8 elems/thread) ----------------
__global__ __launch_bounds__(256) void scale_cvt_kernel(
    const float* __restrict__ x, const float* __restrict__ ns,
    unsigned short* __restrict__ xb) {
  int t = blockIdx.x * 256 + threadIdx.x;  // one 8-elem chunk of a 256-wide row
  if (t >= NN * 32) return;
  int node = t >> 5;
  float sc = ns[node];
  float4 v1 = reinterpret_cast<const float4*>(x)[t * 2];
  float4 v2 = reinterpret_cast<const float4*>(x)[t * 2 + 1];
  uint4 o;
  o.x = f2bf(v1.x * sc) | ((unsigned)f2bf(v1.y * sc) << 16);
  o.y = f2bf(v1.z * sc) | ((unsigned)f2bf(v1.w * sc) << 16);
  o.z = f2bf(v2.x * sc) | ((unsigned)f2bf(v2.y * sc) << 16);
  o.w = f2bf(v2.z * sc) | ((unsigned)f2bf(v2.w * sc) << 16);
  reinterpret_cast<uint4*>(xb)[t] = o;
}

// ---------------- bf16 CSR gather: out[i] = SUM in[col[e]] (rows pre-scaled) --------
// 16 B/lane (8 bf16); LPN = F/8 lanes per node.
// EPI==0: bf16 sum -> out.
// EPI==1: v = sum*sDst+bias; bf16(v*snext[node]) -> out AND sigmoid(v) -> out2 (f32).
// EPI==2: v = sum*sDst+bias; sigmoid(v) -> out2 only.
template <int F, int EPI>
__global__ __launch_bounds__(256) void gatherb_kernel(
    const unsigned short* __restrict__ in, const int* __restrict__ rowptr,
    const int* __restrict__ col, const float* __restrict__ sDst,
    const float* __restrict__ bias, const float* __restrict__ snext,
    unsigned short* __restrict__ out, float* __restrict__ out2, int n) {
  constexpr int LPN = F / 8;
  constexpr int NPB = 256 / LPN;
  const int tid = threadIdx.x;
  const int node = blockIdx.x * NPB + tid / LPN;
  const int j = tid % LPN;
  if (node >= n) return;
  const int e0 = rowptr[node], e1 = rowptr[node + 1];
  float a[8] = {0.f, 0.f, 0.f, 0.f, 0.f, 0.f, 0.f, 0.f};
  for (int e = e0; e < e1; ++e) {
    int c = col[e];
    uint4 u = *reinterpret_cast<const uint4*>(in + (size_t)c * F + j * 8);
    a[0] += __uint_as_float(u.x << 16);
    a[1] += __uint_as_float(u.x & 0xffff0000u);
    a[2] += __uint_as_float(u.y << 16);
    a[3] += __uint_as_float(u.y & 0xffff0000u);
    a[4] += __uint_as_float(u.z << 16);
    a[5] += __uint_as_float(u.z & 0xffff0000u);
    a[6] += __uint_as_float(u.w << 16);
    a[7] += __uint_as_float(u.w & 0xffff0000u);
  }
  if (EPI == 0) {
    uint4 o;
    o.x = f2bf(a[0]) | ((unsigned)f2bf(a[1]) << 16);
    o.y = f2bf(a[2]) | ((unsigned)f2bf(a[3]) << 16);
    o.z = f2bf(a[4]) | ((unsigned)f2bf(a[5]) << 16);
    o.w = f2bf(a[6]) | ((unsigned)f2bf(a[7]) << 16);
    *reinterpret_cast<uint4*>(out + (size_t)node * F + j * 8) = o;
    return;
  }
  const float sd = sDst[node];
  float v[8];
#pragma unroll
  for (int k = 0; k < 8; ++k) v[k] = a[k] * sd + bias[j * 8 + k];
  if (EPI == 1) {
    float sn = snext[node];
    uint4 o;
    o.x = f2bf(v[0] * sn) | ((unsigned)f2bf(v[1] * sn) << 16);
    o.y = f2bf(v[2] * sn) | ((unsigned)f2bf(v[3] * sn) << 16);
    o.z = f2bf(v[4] * sn) | ((unsigned)f2bf(v[5] * sn) << 16);
    o.w = f2bf(v[6] * sn) | ((unsigned)f2bf(v[7] * sn) << 16);
    *reinterpret_cast<uint4*>(out + (size_t)node * F + j * 8) = o;
  }
  float4 s1, s2;
  s1.x = 1.0f / (1.0f + expf(-v[0]));
  s1.y = 1.0f / (1.0f + expf(-v[1]));
  s1.z = 1.0f / (1.0f + expf(-v[2]));
  s1.w = 1.0f / (1.0f + expf(-v[3]));
  s2.x = 1.0f / (1.0f + expf(-v[4]));
  s2.y = 1.0f / (1.0f + expf(-v[5]));
  s2.z = 1.0f / (1.0f + expf(-v[6]));
  s2.w = 1.0f / (1.0f + expf(-v[7]));
  *reinterpret_cast<float4*>(out2 + (size_t)node * F + j * 8) = s1;
  *reinterpret_cast<float4*>(out2 + (size_t)node * F + j * 8 + 4) = s2;
}

// ================= gemm8s: small-K GEMM (K = KT*32, KT<=8) — r10-proven ===========
template <int KT, int RELU>
__global__ __launch_bounds__(256) void gemm8s_kernel(
    const unsigned short* __restrict__ A, const unsigned short* __restrict__ Bt,
    unsigned short* __restrict__ C, int M, int Nreal, int NTn,
    const float* __restrict__ rowscale, const float* __restrict__ bias) {
  constexpr int K = KT * 32;
  constexpr int CPR = KT * 4;            // 16B chunks per LDS row
  constexpr int ROWB = CPR * 16;
  constexpr int TC = 64 * CPR;           // total chunks
  __shared__ __align__(16) char lds[64 * ROWB];

  const int sw = xcd_swizzle(blockIdx.x, gridDim.x);
  const int mg = sw / NTn, nt = sw - mg * NTn;  // n-fastest within XCD chunk
  const int tid = threadIdx.x;
  const int l = tid & 63, w = tid >> 6;
  const int lrow = l & 15, k16 = l >> 4;
  const int m0 = mg * 128 + w * 32, n0 = nt * 64;

  // ---- stage B[64][K] -> LDS (linear dest, inverse-swizzled source) ----
#pragma unroll
  for (int i = 0; i < TC / 256; ++i) {
    int c = i * 256 + tid;
    int row = c / CPR, lch = c % CPR;
    int gch = (lch & ~7) | ((lch & 7) ^ (row & 7));
    const unsigned short* gp = Bt + (size_t)(n0 + row) * K + gch * 8;
    __builtin_amdgcn_global_load_lds(
        (const __attribute__((address_space(1))) void*)gp,
        (__attribute__((address_space(3))) void*)(lds + (i * 256 + w * 64) * 16), 16, 0, 0);
  }

  // ---- issue ALL A-frags (independent of LDS) ----
  bf16x8 af[KT][2];
#pragma unroll
  for (int t = 0; t < KT; ++t)
#pragma unroll
    for (int mi = 0; mi < 2; ++mi)
      af[t][mi] = *reinterpret_cast<const bf16x8*>(
          A + (size_t)(m0 + mi * 16 + lrow) * K + t * 32 + k16 * 8);

  __syncthreads();  // single barrier: drains staging (and A-frags)

  // ---- pure LDS + MFMA burst ----
  f32x4 acc[2][4] = {};
#pragma unroll
  for (int t = 0; t < KT; ++t) {
    bf16x8 bf[4];
#pragma unroll
    for (int ni = 0; ni < 4; ++ni) {
      int row = ni * 16 + lrow;
      int ch = t * 4 + k16;
      int sc = (ch & ~7) | ((ch & 7) ^ (row & 7));
      bf[ni] = *reinterpret_cast<const bf16x8*>(lds + row * ROWB + sc * 16);
    }
#pragma unroll
    for (int mi = 0; mi < 2; ++mi)
#pragma unroll
      for (int ni = 0; ni < 4; ++ni)
        acc[mi][ni] = __builtin_amdgcn_mfma_f32_16x16x32_bf16(af[t][mi], bf[ni], acc[mi][ni], 0, 0, 0);
  }

  // ---- epilogue ----
#pragma unroll
  for (int mi = 0; mi < 2; ++mi) {
#pragma unroll
    for (int q = 0; q < 4; ++q) {
      int r = m0 + mi * 16 + k16 * 4 + q;
      if (r >= M) continue;
      float rs = rowscale[r];
#pragma unroll
      for (int ni = 0; ni < 4; ++ni) {
        int c = n0 + ni * 16 + lrow;
        if (c >= Nreal) continue;
        float v = acc[mi][ni][q] * rs + bias[c];
        if (RELU) v = fmaxf(v, 0.f);
        C[(size_t)r * Nreal + c] = f2bf(v);
      }
    }
  }
}

// ================= gemm8l: K=800 GEMM, B-tile staged in 2 LDS phases — r10-proven ==
template <int OUT_BF>
__global__ __launch_bounds__(256) void gemm8l_kernel(
    const unsigned short* __restrict__ A, const unsigned short* __restrict__ Bt,
    void* __restrict__ C, int M, int N, int NTn,
    const float* __restrict__ rowscale) {
  constexpr int K = 800, KPAD = 832;
  constexpr int CPR = 52;               // chunks per row per phase
  constexpr int ROWB = CPR * 16;
  __shared__ __align__(16) char lds[64 * ROWB];  // 52 KB

  const int sw = xcd_swizzle(blockIdx.x, gridDim.x);
  const int mg = sw / NTn, nt = sw - mg * NTn;
  const int tid = threadIdx.x;
  const int l = tid & 63, w = tid >> 6;
  const int lrow = l & 15, k16 = l >> 4;
  const int m0 = mg * 128 + w * 32, n0 = nt * 64;

  auto stage = [&](int phase) {
#pragma unroll
    for (int i = 0; i < 13; ++i) {  // 64*52/256
      int c = i * 256 + tid;
      int row = c / CPR, lch = c % CPR;
      int gch = phase * CPR + ((lch & ~3) | ((lch & 3) ^ (row & 3)));
      const unsigned short* gp = Bt + (size_t)(n0 + row) * KPAD + gch * 8;
      __builtin_amdgcn_global_load_lds(
          (const __attribute__((address_space(1))) void*)gp,
          (__attribute__((address_space(3))) void*)(lds + (i * 256 + w * 64) * 16), 16, 0, 0);
    }
  };

  f32x4 acc[2][4] = {};

  auto compute = [&](int t0, int t1, int phase) {
#pragma unroll 13
    for (int t = t0; t < t1; ++t) {
      bf16x8 a[2];
#pragma unroll
      for (int mi = 0; mi < 2; ++mi)
        a[mi] = *reinterpret_cast<const bf16x8*>(
            A + (size_t)(m0 + mi * 16 + lrow) * K + t * 32 + k16 * 8);
      bf16x8 bf[4];
#pragma unroll
      for (int ni = 0; ni < 4; ++ni) {
        int row = ni * 16 + lrow;
        int ch = t * 4 + k16 - phase * CPR;
        int sc = (ch & ~3) | ((ch & 3) ^ (row & 3));
        bf[ni] = *reinterpret_cast<const bf16x8*>(lds + row * ROWB + sc * 16);
      }
#pragma unroll
      for (int mi = 0; mi < 2; ++mi)
#pragma unroll
        for (int ni = 0; ni < 4; ++ni)
          acc[mi][ni] = __builtin_amdgcn_mfma_f32_16x16x32_bf16(a[mi], bf[ni], acc[mi][ni], 0, 0, 0);
    }
  };

  stage(0);
  __syncthreads();
  compute(0, 13, 0);      // chunks 0..51
  __syncthreads();        // all waves done with phase-0 LDS
  stage(1);
  __syncthreads();
  compute(13, 25, 1);     // chunks 52..99 (local 0..47)

#pragma unroll
  for (int mi = 0; mi < 2; ++mi) {
#pragma unroll
    for (int q = 0; q < 4; ++q) {
      int r = m0 + mi * 16 + k16 * 4 + q;
      if (r >= M) continue;
      float rs = rowscale[r];
#pragma unroll
      for (int ni = 0; ni < 4; ++ni) {
        int c = n0 + ni * 16 + lrow;
        float v = acc[mi][ni][q] * rs;
        if (OUT_BF) ((unsigned short*)C)[(size_t)r * N + c] = f2bf(v);
        else ((float*)C)[(size_t)r * N + c] = v;
      }
    }
  }
}

extern "C" void kernel_launch(void* const* d_in, const int* in_sizes, int n_in,
                              void* d_out, int out_size, void* d_ws, size_t ws_size,
                              hipStream_t stream) {
  const float* x  = (const float*)d_in[0];
  const int* src  = (const int*)d_in[1];
  const int* dst  = (const int*)d_in[2];
  const float* W1 = (const float*)d_in[3];
  const float* b1 = (const float*)d_in[4];
  const float* W2 = (const float*)d_in[5];
  const float* b2 = (const float*)d_in[6];
  const float* W3 = (const float*)d_in[7];
  const float* b3 = (const float*)d_in[8];
  const float* W4 = (const float*)d_in[9];
  const float* b4 = (const float*)d_in[10];

  float* out_enc = (float*)d_out;                  // [NN,128]
  float* out_dec = out_enc + (size_t)NN * 128;     // [NN,256]

  // ---- workspace layout (~82 MB) ----
  float* ns = (float*)d_ws;                        // [NN]
  float* nd = ns + NN;                             // [NN]
  unsigned short* xb  = (unsigned short*)(nd + NN);  // [NN*256]  bf16(x*ns)
  unsigned short* T2b = xb + (size_t)NN * 256;     // [NN*128] bf16 (gemm8l-L2 out)
  unsigned short* h2  = T2b + (size_t)NN * 128;    // [NN*128] bf16 (h2 * ns, L3 gather src)
  unsigned short* A1  = h2 + (size_t)NN * 128;     // [MROWS*256]
  unsigned short* A3  = A1 + (size_t)MROWS * 256;  // [MROWS*128]
  unsigned short* G4  = A3 + (size_t)MROWS * 128;  // [NN*256] bf16 (gemm8l-L4 out)
  unsigned short* H1  = G4 + (size_t)NN * 256;     // [MH*800] bf16 (gemm8s out)
  unsigned short* W1t = H1 + (size_t)MH * 800;     // [832*256]
  unsigned short* W2t = W1t + 832 * 256;           // [128*832]
  unsigned short* W3t = W2t + 128 * 832;           // [832*128]
  unsigned short* W4t = W3t + 832 * 128;           // [256*832]
  int* degs   = (int*)(W4t + 256 * 832);           // [NN]
  int* degd   = degs + NN;                         // [NN]
  int* cursor = degd + NN;                         // [NN]
  int* rowptr = cursor + NN;                       // [NN+1]
  int* col    = rowptr + NN + 1;                   // [NE]

  // ---- CSR build + norms ----
  (void)hipMemsetAsync(degs, 0, 3 * NN * sizeof(int), stream);
  deg_count_kernel<<<(NE + 255) / 256, 256, 0, stream>>>(src, dst, degs, degd, NE);
  norm_kernel<<<(NN + 255) / 256, 256, 0, stream>>>(degs, degd, ns, nd, NN);
  scan_kernel<<<1, 1024, 0, stream>>>(degd, rowptr, NN);
  csr_fill_kernel<<<(NE + 255) / 256, 256, 0, stream>>>(src, dst, rowptr, cursor, col, NE);

  // ---- weight conversion: Wt[Npad][Kpad] bf16 ----
  wt_convert_kernel<<<dim3(1, 832), 256, 0, stream>>>(W1, W1t, 256, 800, 256);
  wt_convert_kernel<<<dim3(4, 128), 256, 0, stream>>>(W2, W2t, 800, 128, 832);
  wt_convert_kernel<<<dim3(1, 832), 256, 0, stream>>>(W3, W3t, 128, 800, 128);
  wt_convert_kernel<<<dim3(4, 256), 256, 0, stream>>>(W4, W4t, 800, 256, 832);

  // grids
  const int GS = 157 * 13;   // gemm8s L1/L3 (Npad 832)
  const int GL2 = 157 * 2;   // gemm8l L2 (N=128)
  const int GL4 = 157 * 4;   // gemm8l L4 (N=256)

  // ---- L1: xb = bf16(x*ns); gather -> A1; gemm8s (K=256 -> 800) relu -> H1 ----
  scale_cvt_kernel<<<(NN * 32 + 255) / 256, 256, 0, stream>>>(x, ns, xb);
  gatherb_kernel<256, 0><<<(NN + 7) / 8, 256, 0, stream>>>(
      xb, rowptr, col, nullptr, nullptr, nullptr, A1, nullptr, NN);
  gemm8s_kernel<8, 1><<<GS, 256, 0, stream>>>(A1, W1t, H1, NN, 800, 13, nd, b1);

  // ---- L2: gemm8l (800 -> 128)*ns -> bf16 T2b; gather -> h2s=bf16(h2*ns) + sigmoid ----
  gemm8l_kernel<1><<<GL2, 256, 0, stream>>>(H1, W2t, T2b, NN, 128, 2, ns);
  gatherb_kernel<128, 1><<<(NN + 15) / 16, 256, 0, stream>>>(
      T2b, rowptr, col, nd, b2, ns, h2, out_enc, NN);

  // ---- L3: gather(h2s) -> A3; gemm8s (K=128 -> 800) relu -> H1 ----
  gatherb_kernel<128, 0><<<(NN + 15) / 16, 256, 0, stream>>>(
      h2, rowptr, col, nullptr, nullptr, nullptr, A3, nullptr, NN);
  gemm8s_kernel<4, 1><<<GS, 256, 0, stream>>>(A3, W3t, H1, NN, 800, 13, nd, b3);

  // ---- L4: gemm8l (800 -> 256)*ns -> bf16 G4; gather -> sigmoid(out_dec) ----
  gemm8l_kernel<1><<<GL4, 256, 0, stream>>>(H1, W4t, G4, NN, 256, 4, ns);
  gatherb_kernel<256, 2><<<(NN + 7) / 8, 256, 0, stream>>>(
      G4, rowptr, col, nd, b4, nullptr, nullptr, out_dec, NN);
}